// Round 2
// baseline (165.435 us; speedup 1.0000x reference)
//
#include <hip/hip_runtime.h>

// TripletAngularMarginLoss: bs=16384, d=64 (== number of classes)
// out = mean(relu(0.5 + ap - an)) + mean(relu(0.8-ap)) + mean(relu(an-0.4)) + CE
// where ap[i] = min_{t[j]==t[i]} cos(x_i,x_j), an[i] = max_{t[j]!=t[i]} cos(x_i,x_j)

#define N_ROWS 16384
#define N_DIM 64

typedef __attribute__((ext_vector_type(8))) short bf16x8;
typedef __attribute__((ext_vector_type(4))) float f32x4;

__device__ inline unsigned short f2bf(float f) {
  unsigned u = __float_as_uint(f);
  unsigned r = u + 0x7fffu + ((u >> 16) & 1u);   // round-to-nearest-even
  return (unsigned short)(r >> 16);
}

// order-preserving float->uint encoding for atomicMin/atomicMax
__device__ inline unsigned enc_key(float f) {
  unsigned u = __float_as_uint(f);
  return (u & 0x80000000u) ? ~u : (u | 0x80000000u);
}
__device__ inline float dec_key(unsigned k) {
  unsigned u = (k & 0x80000000u) ? (k ^ 0x80000000u) : ~k;
  return __uint_as_float(u);
}

// async global->LDS DMA, 16B per lane, dest = lds_base + lane*16 (linear)
__device__ inline void g2lds16(const void* g, void* l) {
  __builtin_amdgcn_global_load_lds(
      (const __attribute__((address_space(1))) void*)g,
      (__attribute__((address_space(3))) void*)l, 16, 0, 0);
}

// ---------------- Kernel A: normalize rows, emit bf16 copy, per-row CE -------
// Also initializes the min/max key arrays and zeroes the output accumulator
// (replaces two hipMemsetAsync graph nodes; R1 showed ~59us of non-mine time).
__global__ void prep_kernel(const float* __restrict__ x, const int* __restrict__ tgt,
                            unsigned short* __restrict__ xb, float* __restrict__ ce_row,
                            unsigned* __restrict__ mp_key, unsigned* __restrict__ mn_key,
                            float* __restrict__ out) {
  const int row  = blockIdx.x * 4 + (threadIdx.x >> 6);
  const int lane = threadIdx.x & 63;
  float v  = x[row * N_DIM + lane];
  float ss = v * v;
#pragma unroll
  for (int s = 1; s < 64; s <<= 1) ss += __shfl_xor(ss, s, 64);
  float xn = v * rsqrtf(ss);
  xb[row * N_DIM + lane] = f2bf(xn);

  // log-softmax over the 64 normalized features
  float mx = xn;
#pragma unroll
  for (int s = 1; s < 64; s <<= 1) mx = fmaxf(mx, __shfl_xor(mx, s, 64));
  float e  = __expf(xn - mx);
  float se = e;
#pragma unroll
  for (int s = 1; s < 64; s <<= 1) se += __shfl_xor(se, s, 64);
  float lse = mx + __logf(se);
  int   t   = tgt[row];                 // wave-uniform
  float xt  = __shfl(xn, t, 64);
  if (lane == 0) {
    ce_row[row] = lse - xt;
    mp_key[row] = 0xFFFFFFFFu;          // +inf key for atomicMin
    mn_key[row] = 0u;                   // -inf key for atomicMax
  }
  if (blockIdx.x == 0 && threadIdx.x == 0) out[0] = 0.f;
}

// ---------------- Kernel B: MFMA similarity tiles + hard mining --------------
// grid = 64 i-blocks * 16 j-splits = 1024 blocks of 256 threads (4 waves) =
// exactly 4 blocks/CU (one full residency pass with __launch_bounds__(256,4)).
// B tiles staged ONCE per block into LDS via global_load_lds (waves 0/1 DMA
// half each), double-buffered dist-1; layout XOR-swizzled (byte ^= (col&7)<<4)
// with the inverse swizzle applied to the per-lane GLOBAL source address so the
// ds_read_b128 fragment reads are bank-balanced.
// R1 fix: row-targets packed 4x8bit/VGPR (ti 16 regs -> tip 4 regs) so live
// state (~100 VGPR) fits the 128-VGPR cap of 4 waves/EU. R1 measured VGPR=56 +
// WRITE_SIZE=8MB (scratch spill traffic) with the unpacked version.
__global__ __launch_bounds__(256, 4)
void mine_kernel(const unsigned short* __restrict__ xb, const int* __restrict__ tgt,
                 unsigned* __restrict__ mp_key, unsigned* __restrict__ mn_key) {
  __shared__ unsigned short Bt[2][1024];  // 2 x 2KB: 16 cols x 64 dims, swizzled
  __shared__ int tjl[N_ROWS / 16];        // 4KB: targets of this block's j-range

  const int lane    = threadIdx.x & 63;
  const int wv      = threadIdx.x >> 6;
  const int iblk    = blockIdx.x >> 4;
  const int jspl    = blockIdx.x & 15;
  const int rowbase = iblk * 256 + wv * 64;
  const int m = lane & 15, q = lane >> 4;
  const int jbase = jspl * (N_ROWS / 16);

  // A fragments: lane holds row (rowbase+tr*16+m), k = q*8..q*8+7 (+32 for ks=1)
  bf16x8 a[4][2];
#pragma unroll
  for (int tr = 0; tr < 4; ++tr) {
    const unsigned short* p = xb + (rowbase + tr * 16 + m) * N_DIM + q * 8;
    a[tr][0] = *(const bf16x8*)(p);
    a[tr][1] = *(const bf16x8*)(p + 32);
  }
  // row targets for the C/D rows this lane owns (row = tr*16 + q*4 + r),
  // packed 4 per VGPR as 8-bit fields (targets are < 64)
  unsigned tip[4];
#pragma unroll
  for (int tr = 0; tr < 4; ++tr) {
    unsigned vv = 0;
#pragma unroll
    for (int r = 0; r < 4; ++r)
      vv |= ((unsigned)tgt[rowbase + tr * 16 + q * 4 + r] & 0xffu) << (8 * r);
    tip[tr] = vv;
  }

  float mp[16], mn[16];
#pragma unroll
  for (int k = 0; k < 16; ++k) { mp[k] = __builtin_inff(); mn[k] = -__builtin_inff(); }

  // preload j-range targets into LDS (read per jc as ds_read, conflict-free)
  for (int k = threadIdx.x; k < N_ROWS / 16; k += 256) tjl[k] = tgt[jbase + k];

  // Staging source address (per-lane, pre-swizzled):
  // stage-wave wv in {0,1} fills tile bytes [wv*1024 + lane*16, +16).
  // Inverse of read swizzle: col = wv*8 + (lane>>3), dimgrp = (lane&7)^((lane>>3)&7)
  const unsigned short* srcbase =
      xb + (jbase + wv * 8 + (lane >> 3)) * N_DIM +
      (((lane & 7) ^ ((lane >> 3) & 7)) * 8);

  if (wv < 2) g2lds16(srcbase, &Bt[0][wv * 512]);   // prologue: stage jc=0
  __syncthreads();

  // swizzled fragment-read byte offsets (constant per lane):
  // col m's 128B block, dim-offset XOR'd by (m&7)<<4
  const int roff0 = m * 128 + ((q * 16) ^ ((m & 7) << 4));
  const int roff1 = m * 128 + (((64) + q * 16) ^ ((m & 7) << 4));

  for (int jc = 0; jc < 64; ++jc) {
    const int p = jc & 1;
    // fire DMA for tile jc+1 into the other buffer (hidden under compute)
    if (wv < 2 && jc < 63)
      g2lds16(srcbase + (jc + 1) * 16 * N_DIM, &Bt[p ^ 1][wv * 512]);

    const char* bb = (const char*)&Bt[p][0];
    const bf16x8 cb0 = *(const bf16x8*)(bb + roff0);
    const bf16x8 cb1 = *(const bf16x8*)(bb + roff1);
    const unsigned ctj = (unsigned)tjl[jc * 16 + m] & 0xffu;

#pragma unroll
    for (int tr = 0; tr < 4; ++tr) {
      f32x4 acc = {0.f, 0.f, 0.f, 0.f};
      acc = __builtin_amdgcn_mfma_f32_16x16x32_bf16(a[tr][0], cb0, acc, 0, 0, 0);
      acc = __builtin_amdgcn_mfma_f32_16x16x32_bf16(a[tr][1], cb1, acc, 0, 0, 0);
#pragma unroll
      for (int r = 0; r < 4; ++r) {
        const bool  pos = (((tip[tr] >> (8 * r)) & 0xffu) == ctj);
        const float d   = acc[r];
        const int   k   = tr * 4 + r;
        mp[k] = fminf(mp[k], pos ? d : __builtin_inff());
        mn[k] = fmaxf(mn[k], pos ? -__builtin_inff() : d);
      }
    }
    __syncthreads();   // drains wv0/1 DMA (vmcnt) + everyone's ds reads, then barrier
  }

  // reduce across the 16 lanes (m = 0..15) inside each q-group
#pragma unroll
  for (int s = 1; s < 16; s <<= 1) {
#pragma unroll
    for (int k = 0; k < 16; ++k) {
      mp[k] = fminf(mp[k], __shfl_xor(mp[k], s, 64));
      mn[k] = fmaxf(mn[k], __shfl_xor(mn[k], s, 64));
    }
  }
  if (m == 0) {
#pragma unroll
    for (int tr = 0; tr < 4; ++tr)
#pragma unroll
      for (int r = 0; r < 4; ++r) {
        const int row = rowbase + tr * 16 + q * 4 + r;
        atomicMin(&mp_key[row], enc_key(mp[tr * 4 + r]));
        atomicMax(&mn_key[row], enc_key(mn[tr * 4 + r]));
      }
  }
}

// ---------------- Kernel C: final reduction (8 blocks, float atomicAdd) ------
__global__ void finalize_kernel(const unsigned* __restrict__ mp_key, const unsigned* __restrict__ mn_key,
                                const float* __restrict__ ce_row, float* __restrict__ out) {
  __shared__ float red[16];
  float s = 0.f;
#pragma unroll
  for (int it = 0; it < 2; ++it) {
    const int r = it * 8192 + blockIdx.x * 1024 + threadIdx.x;
    float ap = dec_key(mp_key[r]);
    float an = dec_key(mn_key[r]);
    s += fmaxf(0.5f + ap - an, 0.f) + fmaxf(0.8f - ap, 0.f) +
         fmaxf(an - 0.4f, 0.f) + ce_row[r];
  }
#pragma unroll
  for (int sh = 1; sh < 64; sh <<= 1) s += __shfl_xor(s, sh, 64);
  const int wv = threadIdx.x >> 6;
  if ((threadIdx.x & 63) == 0) red[wv] = s;
  __syncthreads();
  if (threadIdx.x == 0) {
    float t = 0.f;
#pragma unroll
    for (int w = 0; w < 16; ++w) t += red[w];
    atomicAdd(out, t * (1.0f / N_ROWS));
  }
}

extern "C" void kernel_launch(void* const* d_in, const int* in_sizes, int n_in,
                              void* d_out, int out_size, void* d_ws, size_t ws_size,
                              hipStream_t stream) {
  const float* x   = (const float*)d_in[0];
  const int*   tgt = (const int*)d_in[1];
  char* ws = (char*)d_ws;

  unsigned short* xb     = (unsigned short*)ws;                          // 2 MB bf16 normalized
  unsigned*       mp_key = (unsigned*)(ws + (2u << 20));                 // 64 KB
  unsigned*       mn_key = (unsigned*)(ws + (2u << 20) + (64u << 10));   // 64 KB
  float*          ce_row = (float*)(ws + (2u << 20) + (128u << 10));     // 64 KB
  float*          out    = (float*)d_out;

  prep_kernel<<<N_ROWS / 4, 256, 0, stream>>>(x, tgt, xb, ce_row, mp_key, mn_key, out);
  mine_kernel<<<(N_ROWS / 256) * 16, 256, 0, stream>>>(xb, tgt, mp_key, mn_key);
  finalize_kernel<<<8, 1024, 0, stream>>>(mp_key, mn_key, ce_row, out);
}

// Round 3
// 163.528 us; speedup vs baseline: 1.0117x; 1.0117x over previous
//
#include <hip/hip_runtime.h>

// TripletAngularMarginLoss: bs=16384, d=64 (== number of classes)
// out = mean(relu(0.5 + ap - an)) + mean(relu(0.8-ap)) + mean(relu(an-0.4)) + CE
// where ap[i] = min_{t[j]==t[i]} cos(x_i,x_j), an[i] = max_{t[j]!=t[i]} cos(x_i,x_j)

#define N_ROWS 16384
#define N_DIM 64

typedef __attribute__((ext_vector_type(8))) short bf16x8;
typedef __attribute__((ext_vector_type(4))) float f32x4;

__device__ inline unsigned short f2bf(float f) {
  unsigned u = __float_as_uint(f);
  unsigned r = u + 0x7fffu + ((u >> 16) & 1u);   // round-to-nearest-even
  return (unsigned short)(r >> 16);
}

// order-preserving float->uint encoding for atomicMin/atomicMax
__device__ inline unsigned enc_key(float f) {
  unsigned u = __float_as_uint(f);
  return (u & 0x80000000u) ? ~u : (u | 0x80000000u);
}
__device__ inline float dec_key(unsigned k) {
  unsigned u = (k & 0x80000000u) ? (k ^ 0x80000000u) : ~k;
  return __uint_as_float(u);
}

// async global->LDS DMA, 16B per lane, dest = lds_base + lane*16 (linear)
__device__ inline void g2lds16(const void* g, void* l) {
  __builtin_amdgcn_global_load_lds(
      (const __attribute__((address_space(1))) void*)g,
      (__attribute__((address_space(3))) void*)l, 16, 0, 0);
}

// ---------------- Kernel A: normalize rows, emit bf16 copy, per-row CE -------
// Also initializes the min/max key arrays and zeroes the output accumulator.
__global__ void prep_kernel(const float* __restrict__ x, const int* __restrict__ tgt,
                            unsigned short* __restrict__ xb, float* __restrict__ ce_row,
                            unsigned* __restrict__ mp_key, unsigned* __restrict__ mn_key,
                            float* __restrict__ out) {
  const int row  = blockIdx.x * 4 + (threadIdx.x >> 6);
  const int lane = threadIdx.x & 63;
  float v  = x[row * N_DIM + lane];
  float ss = v * v;
#pragma unroll
  for (int s = 1; s < 64; s <<= 1) ss += __shfl_xor(ss, s, 64);
  float xn = v * rsqrtf(ss);
  xb[row * N_DIM + lane] = f2bf(xn);

  // log-softmax over the 64 normalized features
  float mx = xn;
#pragma unroll
  for (int s = 1; s < 64; s <<= 1) mx = fmaxf(mx, __shfl_xor(mx, s, 64));
  float e  = __expf(xn - mx);
  float se = e;
#pragma unroll
  for (int s = 1; s < 64; s <<= 1) se += __shfl_xor(se, s, 64);
  float lse = mx + __logf(se);
  int   t   = tgt[row];                 // wave-uniform
  float xt  = __shfl(xn, t, 64);
  if (lane == 0) {
    ce_row[row] = lse - xt;
    mp_key[row] = 0xFFFFFFFFu;          // +inf key for atomicMin
    mn_key[row] = 0u;                   // -inf key for atomicMax
  }
  if (blockIdx.x == 0 && threadIdx.x == 0) out[0] = 0.f;
}

// ---------------- Kernel B: MFMA similarity tiles + hard mining --------------
// grid = 64 i-blocks * 16 j-splits = 1024 blocks of 256 threads (4 waves) =
// exactly 4 blocks/CU (one full residency pass).
// B tiles staged ONCE per block into LDS via global_load_lds (waves 0/1 DMA
// half each), double-buffered dist-1; layout XOR-swizzled so the ds_read_b128
// fragment reads are bank-balanced.
// R2 evidence: VGPR_Count=64 (8-wave/EU boundary) + WRITE_SIZE=8192KB exactly
// (= 32B/thread scratch spill) — backend chased max occupancy, spilled the
// loop state, and shuffled the rest through AGPRs (VALUBusy 68% mostly
// accvgpr moves). Fix: pin waves/EU to EXACTLY 4 so the allocator gets the
// full 128-VGPR budget (live state ~100 regs) with zero spill.
__global__ __attribute__((amdgpu_flat_work_group_size(256, 256),
                          amdgpu_waves_per_eu(4, 4)))
void mine_kernel(const unsigned short* __restrict__ xb, const int* __restrict__ tgt,
                 unsigned* __restrict__ mp_key, unsigned* __restrict__ mn_key) {
  __shared__ unsigned short Bt[2][1024];  // 2 x 2KB: 16 cols x 64 dims, swizzled
  __shared__ int tjl[N_ROWS / 16];        // 4KB: targets of this block's j-range

  const int lane    = threadIdx.x & 63;
  const int wv      = threadIdx.x >> 6;
  const int iblk    = blockIdx.x >> 4;
  const int jspl    = blockIdx.x & 15;
  const int rowbase = iblk * 256 + wv * 64;
  const int m = lane & 15, q = lane >> 4;
  const int jbase = jspl * (N_ROWS / 16);

  // A fragments: lane holds row (rowbase+tr*16+m), k = q*8..q*8+7 (+32 for ks=1)
  bf16x8 a[4][2];
#pragma unroll
  for (int tr = 0; tr < 4; ++tr) {
    const unsigned short* p = xb + (rowbase + tr * 16 + m) * N_DIM + q * 8;
    a[tr][0] = *(const bf16x8*)(p);
    a[tr][1] = *(const bf16x8*)(p + 32);
  }
  // row targets for the C/D rows this lane owns (row = tr*16 + q*4 + r),
  // packed 4 per VGPR as 8-bit fields (targets are < 64)
  unsigned tip[4];
#pragma unroll
  for (int tr = 0; tr < 4; ++tr) {
    unsigned vv = 0;
#pragma unroll
    for (int r = 0; r < 4; ++r)
      vv |= ((unsigned)tgt[rowbase + tr * 16 + q * 4 + r] & 0xffu) << (8 * r);
    tip[tr] = vv;
  }

  float mp[16], mn[16];
#pragma unroll
  for (int k = 0; k < 16; ++k) { mp[k] = __builtin_inff(); mn[k] = -__builtin_inff(); }

  // preload j-range targets into LDS (read per jc as ds_read, conflict-free)
  for (int k = threadIdx.x; k < N_ROWS / 16; k += 256) tjl[k] = tgt[jbase + k];

  // Staging source address (per-lane, pre-swizzled):
  // stage-wave wv in {0,1} fills tile bytes [wv*1024 + lane*16, +16).
  // Inverse of read swizzle: col = wv*8 + (lane>>3), dimgrp = (lane&7)^((lane>>3)&7)
  const unsigned short* srcbase =
      xb + (jbase + wv * 8 + (lane >> 3)) * N_DIM +
      (((lane & 7) ^ ((lane >> 3) & 7)) * 8);

  if (wv < 2) g2lds16(srcbase, &Bt[0][wv * 512]);   // prologue: stage jc=0
  __syncthreads();

  // swizzled fragment-read byte offsets (constant per lane):
  // col m's 128B block, dim-offset XOR'd by (m&7)<<4
  const int roff0 = m * 128 + ((q * 16) ^ ((m & 7) << 4));
  const int roff1 = m * 128 + (((64) + q * 16) ^ ((m & 7) << 4));

  for (int jc = 0; jc < 64; ++jc) {
    const int p = jc & 1;
    // fire DMA for tile jc+1 into the other buffer (hidden under compute)
    if (wv < 2 && jc < 63)
      g2lds16(srcbase + (jc + 1) * 16 * N_DIM, &Bt[p ^ 1][wv * 512]);

    const char* bb = (const char*)&Bt[p][0];
    const bf16x8 cb0 = *(const bf16x8*)(bb + roff0);
    const bf16x8 cb1 = *(const bf16x8*)(bb + roff1);
    const unsigned ctj = (unsigned)tjl[jc * 16 + m] & 0xffu;

#pragma unroll
    for (int tr = 0; tr < 4; ++tr) {
      f32x4 acc = {0.f, 0.f, 0.f, 0.f};
      acc = __builtin_amdgcn_mfma_f32_16x16x32_bf16(a[tr][0], cb0, acc, 0, 0, 0);
      acc = __builtin_amdgcn_mfma_f32_16x16x32_bf16(a[tr][1], cb1, acc, 0, 0, 0);
#pragma unroll
      for (int r = 0; r < 4; ++r) {
        const bool  pos = (((tip[tr] >> (8 * r)) & 0xffu) == ctj);
        const float d   = acc[r];
        const int   k   = tr * 4 + r;
        mp[k] = fminf(mp[k], pos ? d : __builtin_inff());
        mn[k] = fmaxf(mn[k], pos ? -__builtin_inff() : d);
      }
    }
    __syncthreads();   // drains wv0/1 DMA (vmcnt) + everyone's ds reads, then barrier
  }

  // reduce across the 16 lanes (m = 0..15) inside each q-group
#pragma unroll
  for (int s = 1; s < 16; s <<= 1) {
#pragma unroll
    for (int k = 0; k < 16; ++k) {
      mp[k] = fminf(mp[k], __shfl_xor(mp[k], s, 64));
      mn[k] = fmaxf(mn[k], __shfl_xor(mn[k], s, 64));
    }
  }
  if (m == 0) {
#pragma unroll
    for (int tr = 0; tr < 4; ++tr)
#pragma unroll
      for (int r = 0; r < 4; ++r) {
        const int row = rowbase + tr * 16 + q * 4 + r;
        atomicMin(&mp_key[row], enc_key(mp[tr * 4 + r]));
        atomicMax(&mn_key[row], enc_key(mn[tr * 4 + r]));
      }
  }
}

// ---------------- Kernel C: final reduction (8 blocks, float atomicAdd) ------
__global__ void finalize_kernel(const unsigned* __restrict__ mp_key, const unsigned* __restrict__ mn_key,
                                const float* __restrict__ ce_row, float* __restrict__ out) {
  __shared__ float red[16];
  float s = 0.f;
#pragma unroll
  for (int it = 0; it < 2; ++it) {
    const int r = it * 8192 + blockIdx.x * 1024 + threadIdx.x;
    float ap = dec_key(mp_key[r]);
    float an = dec_key(mn_key[r]);
    s += fmaxf(0.5f + ap - an, 0.f) + fmaxf(0.8f - ap, 0.f) +
         fmaxf(an - 0.4f, 0.f) + ce_row[r];
  }
#pragma unroll
  for (int sh = 1; sh < 64; sh <<= 1) s += __shfl_xor(s, sh, 64);
  const int wv = threadIdx.x >> 6;
  if ((threadIdx.x & 63) == 0) red[wv] = s;
  __syncthreads();
  if (threadIdx.x == 0) {
    float t = 0.f;
#pragma unroll
    for (int w = 0; w < 16; ++w) t += red[w];
    atomicAdd(out, t * (1.0f / N_ROWS));
  }
}

extern "C" void kernel_launch(void* const* d_in, const int* in_sizes, int n_in,
                              void* d_out, int out_size, void* d_ws, size_t ws_size,
                              hipStream_t stream) {
  const float* x   = (const float*)d_in[0];
  const int*   tgt = (const int*)d_in[1];
  char* ws = (char*)d_ws;

  unsigned short* xb     = (unsigned short*)ws;                          // 2 MB bf16 normalized
  unsigned*       mp_key = (unsigned*)(ws + (2u << 20));                 // 64 KB
  unsigned*       mn_key = (unsigned*)(ws + (2u << 20) + (64u << 10));   // 64 KB
  float*          ce_row = (float*)(ws + (2u << 20) + (128u << 10));     // 64 KB
  float*          out    = (float*)d_out;

  prep_kernel<<<N_ROWS / 4, 256, 0, stream>>>(x, tgt, xb, ce_row, mp_key, mn_key, out);
  mine_kernel<<<(N_ROWS / 256) * 16, 256, 0, stream>>>(xb, tgt, mp_key, mn_key);
  finalize_kernel<<<8, 1024, 0, stream>>>(mp_key, mn_key, ce_row, out);
}

// Round 4
// 159.565 us; speedup vs baseline: 1.0368x; 1.0248x over previous
//
#include <hip/hip_runtime.h>

// TripletAngularMarginLoss: bs=16384, d=64 (== number of classes)
// out = mean(relu(0.5 + ap - an)) + mean(relu(0.8-ap)) + mean(relu(an-0.4)) + CE
// where ap[i] = min_{t[j]==t[i]} cos(x_i,x_j), an[i] = max_{t[j]!=t[i]} cos(x_i,x_j)

#define N_ROWS 16384
#define N_DIM 64

typedef __attribute__((ext_vector_type(8))) short bf16x8;
typedef __attribute__((ext_vector_type(4))) float f32x4;

__device__ inline unsigned short f2bf(float f) {
  unsigned u = __float_as_uint(f);
  unsigned r = u + 0x7fffu + ((u >> 16) & 1u);   // round-to-nearest-even
  return (unsigned short)(r >> 16);
}

// order-preserving float->uint encoding for atomicMin/atomicMax
__device__ inline unsigned enc_key(float f) {
  unsigned u = __float_as_uint(f);
  return (u & 0x80000000u) ? ~u : (u | 0x80000000u);
}
__device__ inline float dec_key(unsigned k) {
  unsigned u = (k & 0x80000000u) ? (k ^ 0x80000000u) : ~k;
  return __uint_as_float(u);
}

// async global->LDS DMA, 16B per lane, dest = lds_base + lane*16 (linear)
__device__ inline void g2lds16(const void* g, void* l) {
  __builtin_amdgcn_global_load_lds(
      (const __attribute__((address_space(1))) void*)g,
      (__attribute__((address_space(3))) void*)l, 16, 0, 0);
}

// ---------------- Kernel A: normalize rows, emit bf16 copy, per-row CE -------
// Also initializes the min/max key arrays and zeroes the output accumulator.
__global__ void prep_kernel(const float* __restrict__ x, const int* __restrict__ tgt,
                            unsigned short* __restrict__ xb, float* __restrict__ ce_row,
                            unsigned* __restrict__ mp_key, unsigned* __restrict__ mn_key,
                            float* __restrict__ out) {
  const int row  = blockIdx.x * 4 + (threadIdx.x >> 6);
  const int lane = threadIdx.x & 63;
  float v  = x[row * N_DIM + lane];
  float ss = v * v;
#pragma unroll
  for (int s = 1; s < 64; s <<= 1) ss += __shfl_xor(ss, s, 64);
  float xn = v * rsqrtf(ss);
  xb[row * N_DIM + lane] = f2bf(xn);

  // log-softmax over the 64 normalized features
  float mx = xn;
#pragma unroll
  for (int s = 1; s < 64; s <<= 1) mx = fmaxf(mx, __shfl_xor(mx, s, 64));
  float e  = __expf(xn - mx);
  float se = e;
#pragma unroll
  for (int s = 1; s < 64; s <<= 1) se += __shfl_xor(se, s, 64);
  float lse = mx + __logf(se);
  int   t   = tgt[row];                 // wave-uniform
  float xt  = __shfl(xn, t, 64);
  if (lane == 0) {
    ce_row[row] = lse - xt;
    mp_key[row] = 0xFFFFFFFFu;          // +inf key for atomicMin
    mn_key[row] = 0u;                   // -inf key for atomicMax
  }
  if (blockIdx.x == 0 && threadIdx.x == 0) out[0] = 0.f;
}

// ---------------- Kernel B: MFMA similarity tiles + hard mining --------------
// R3 post-mortem: WRITE_SIZE == 8192KB == 32B/thread one-time scratch across
// THREE codegen variants; allocator squeezes arch-VGPRs to 56-64 regardless of
// launch_bounds / waves_per_eu, spilling one A-fragment pair that is reloaded
// every jc iteration on the MFMA critical path. Fix: halve per-wave live state
// so the kernel FITS the squeeze target. Each wave owns 2 row-tiles (32 rows);
// grid = 128 i-blocks * 16 j-splits = 2048 blocks of 256 threads = 8 blocks/CU
// (one residency pass at 8 waves/EU, VGPR budget 64, live state ~58).
// B tiles staged per block into LDS via global_load_lds (waves 0/1 DMA half
// each), double-buffered dist-1, XOR-swizzled for bank-balanced ds_read_b128.
__global__ __launch_bounds__(256, 8)
void mine_kernel(const unsigned short* __restrict__ xb, const int* __restrict__ tgt,
                 unsigned* __restrict__ mp_key, unsigned* __restrict__ mn_key) {
  __shared__ unsigned short Bt[2][1024];  // 2 x 2KB: 16 cols x 64 dims, swizzled
  __shared__ int tjl[N_ROWS / 16];        // 4KB: targets of this block's j-range

  const int lane    = threadIdx.x & 63;
  const int wv      = threadIdx.x >> 6;
  const int iblk    = blockIdx.x >> 4;
  const int jspl    = blockIdx.x & 15;
  const int rowbase = iblk * 128 + wv * 32;
  const int m = lane & 15, q = lane >> 4;
  const int jbase = jspl * (N_ROWS / 16);

  // A fragments: lane holds row (rowbase+tr*16+m), k = q*8..q*8+7 (+32 for ks=1)
  bf16x8 a[2][2];
#pragma unroll
  for (int tr = 0; tr < 2; ++tr) {
    const unsigned short* p = xb + (rowbase + tr * 16 + m) * N_DIM + q * 8;
    a[tr][0] = *(const bf16x8*)(p);
    a[tr][1] = *(const bf16x8*)(p + 32);
  }
  // row targets for the C/D rows this lane owns: row = tr*16 + q*4 + r
  int ti[2][4];
#pragma unroll
  for (int tr = 0; tr < 2; ++tr)
#pragma unroll
    for (int r = 0; r < 4; ++r)
      ti[tr][r] = tgt[rowbase + tr * 16 + q * 4 + r];

  float mp[8], mn[8];
#pragma unroll
  for (int k = 0; k < 8; ++k) { mp[k] = __builtin_inff(); mn[k] = -__builtin_inff(); }

  // preload j-range targets into LDS (read per jc as ds_read, conflict-free)
  for (int k = threadIdx.x; k < N_ROWS / 16; k += 256) tjl[k] = tgt[jbase + k];

  // Staging source address (per-lane, pre-swizzled):
  // stage-wave wv in {0,1} fills tile bytes [wv*1024 + lane*16, +16).
  // Inverse of read swizzle: col = wv*8 + (lane>>3), dimgrp = (lane&7)^((lane>>3)&7)
  const unsigned short* srcbase =
      xb + (jbase + wv * 8 + (lane >> 3)) * N_DIM +
      (((lane & 7) ^ ((lane >> 3) & 7)) * 8);

  if (wv < 2) g2lds16(srcbase, &Bt[0][wv * 512]);   // prologue: stage jc=0
  __syncthreads();

  // swizzled fragment-read byte offsets (constant per lane):
  // col m's 128B block, dim-offset XOR'd by (m&7)<<4
  const int roff0 = m * 128 + ((q * 16) ^ ((m & 7) << 4));
  const int roff1 = m * 128 + (((64) + q * 16) ^ ((m & 7) << 4));

  for (int jc = 0; jc < 64; ++jc) {
    const int p = jc & 1;
    // fire DMA for tile jc+1 into the other buffer (hidden under compute)
    if (wv < 2 && jc < 63)
      g2lds16(srcbase + (jc + 1) * 16 * N_DIM, &Bt[p ^ 1][wv * 512]);

    const char* bb = (const char*)&Bt[p][0];
    const bf16x8 cb0 = *(const bf16x8*)(bb + roff0);
    const bf16x8 cb1 = *(const bf16x8*)(bb + roff1);
    const int    ctj = tjl[jc * 16 + m];

#pragma unroll
    for (int tr = 0; tr < 2; ++tr) {
      f32x4 acc = {0.f, 0.f, 0.f, 0.f};
      acc = __builtin_amdgcn_mfma_f32_16x16x32_bf16(a[tr][0], cb0, acc, 0, 0, 0);
      acc = __builtin_amdgcn_mfma_f32_16x16x32_bf16(a[tr][1], cb1, acc, 0, 0, 0);
#pragma unroll
      for (int r = 0; r < 4; ++r) {
        const bool  pos = (ctj == ti[tr][r]);
        const float d   = acc[r];
        const int   k   = tr * 4 + r;
        mp[k] = fminf(mp[k], pos ? d : __builtin_inff());
        mn[k] = fmaxf(mn[k], pos ? -__builtin_inff() : d);
      }
    }
    __syncthreads();   // drains wv0/1 DMA (vmcnt) + everyone's ds reads, then barrier
  }

  // reduce across the 16 lanes (m = 0..15) inside each q-group
#pragma unroll
  for (int s = 1; s < 16; s <<= 1) {
#pragma unroll
    for (int k = 0; k < 8; ++k) {
      mp[k] = fminf(mp[k], __shfl_xor(mp[k], s, 64));
      mn[k] = fmaxf(mn[k], __shfl_xor(mn[k], s, 64));
    }
  }
  if (m == 0) {
#pragma unroll
    for (int tr = 0; tr < 2; ++tr)
#pragma unroll
      for (int r = 0; r < 4; ++r) {
        const int row = rowbase + tr * 16 + q * 4 + r;
        atomicMin(&mp_key[row], enc_key(mp[tr * 4 + r]));
        atomicMax(&mn_key[row], enc_key(mn[tr * 4 + r]));
      }
  }
}

// ---------------- Kernel C: final reduction (8 blocks, float atomicAdd) ------
__global__ void finalize_kernel(const unsigned* __restrict__ mp_key, const unsigned* __restrict__ mn_key,
                                const float* __restrict__ ce_row, float* __restrict__ out) {
  __shared__ float red[16];
  float s = 0.f;
#pragma unroll
  for (int it = 0; it < 2; ++it) {
    const int r = it * 8192 + blockIdx.x * 1024 + threadIdx.x;
    float ap = dec_key(mp_key[r]);
    float an = dec_key(mn_key[r]);
    s += fmaxf(0.5f + ap - an, 0.f) + fmaxf(0.8f - ap, 0.f) +
         fmaxf(an - 0.4f, 0.f) + ce_row[r];
  }
#pragma unroll
  for (int sh = 1; sh < 64; sh <<= 1) s += __shfl_xor(s, sh, 64);
  const int wv = threadIdx.x >> 6;
  if ((threadIdx.x & 63) == 0) red[wv] = s;
  __syncthreads();
  if (threadIdx.x == 0) {
    float t = 0.f;
#pragma unroll
    for (int w = 0; w < 16; ++w) t += red[w];
    atomicAdd(out, t * (1.0f / N_ROWS));
  }
}

extern "C" void kernel_launch(void* const* d_in, const int* in_sizes, int n_in,
                              void* d_out, int out_size, void* d_ws, size_t ws_size,
                              hipStream_t stream) {
  const float* x   = (const float*)d_in[0];
  const int*   tgt = (const int*)d_in[1];
  char* ws = (char*)d_ws;

  unsigned short* xb     = (unsigned short*)ws;                          // 2 MB bf16 normalized
  unsigned*       mp_key = (unsigned*)(ws + (2u << 20));                 // 64 KB
  unsigned*       mn_key = (unsigned*)(ws + (2u << 20) + (64u << 10));   // 64 KB
  float*          ce_row = (float*)(ws + (2u << 20) + (128u << 10));     // 64 KB
  float*          out    = (float*)d_out;

  prep_kernel<<<N_ROWS / 4, 256, 0, stream>>>(x, tgt, xb, ce_row, mp_key, mn_key, out);
  mine_kernel<<<(N_ROWS / 128) * 16, 256, 0, stream>>>(xb, tgt, mp_key, mn_key);
  finalize_kernel<<<8, 1024, 0, stream>>>(mp_key, mn_key, ce_row, out);
}